// Round 6
// baseline (468.413 us; speedup 1.0000x reference)
//
#include <hip/hip_runtime.h>

// FixSetLinearAttention: B=8 T=2048 C=768 NH=12 hs=64 Lmin=16, 255 segments + tail.
// R6: k_veins re-pipelined — B-fragments prefetched a FULL iteration ahead (covers
// ~200cy L2 latency under 32 MFMAs), k read as half8 ds_read_b128 per 8 iters with
// compile-time lane extract (was 32 scalar ds_read_u16/iter, each ~120cy latency).
// Rest identical to R5 (all-fp16 pipeline, 466us, absmax 0.125).

typedef float  f32x4  __attribute__((ext_vector_type(4)));
typedef _Float16 half8 __attribute__((ext_vector_type(8)));
typedef _Float16 half4 __attribute__((ext_vector_type(4)));

#define DEV __device__ __forceinline__
#define MFMA16(a, b, c) __builtin_amdgcn_mfma_f32_16x16x32_f16((a), (b), (c), 0, 0, 0)
#define GLOAD16(gp, lp)                                                  \
  __builtin_amdgcn_global_load_lds(                                      \
      (const __attribute__((address_space(1))) unsigned int*)(gp),       \
      (__attribute__((address_space(3))) unsigned int*)(lp), 16, 0, 0)

// ---------------- prep: f32 -> fp16 ----------------
__global__ __launch_bounds__(256) void k_cast16(const float* __restrict__ in,
                                                _Float16* __restrict__ outh, int n4) {
  int i = blockIdx.x * 256 + threadIdx.x;
  if (i >= n4) return;
  f32x4 v = ((const f32x4*)in)[i];
  half4 o;
#pragma unroll
  for (int c = 0; c < 4; ++c) o[c] = (_Float16)v[c];
  ((half4*)outh)[i] = o;
}

// ---------------- qkv GEMM: C = A @ B^T, fp16 single pass ----------------
__global__ __launch_bounds__(256, 3) void k_gemm_qkv(
    const _Float16* __restrict__ A16, const _Float16* __restrict__ B16,
    _Float16* __restrict__ qo, _Float16* __restrict__ ko, _Float16* __restrict__ v0o) {
  __shared__ _Float16 sA[128][64], sB[128][64];
  const int K = 768;
  int tid = threadIdx.x, lane = tid & 63, wave = tid >> 6;
  int l15 = lane & 15, g = lane >> 4;
  int wr = wave >> 1, wc = wave & 1;
  int n0 = blockIdx.x * 128, m0 = blockIdx.y * 128;
  f32x4 acc[4][4];
#pragma unroll
  for (int a = 0; a < 4; ++a)
#pragma unroll
    for (int b = 0; b < 4; ++b) acc[a][b] = f32x4{0.f, 0.f, 0.f, 0.f};
  int rsel = lane >> 3;            // row within 8-row group; row&7 == rsel
  int csel = (lane & 7) ^ rsel;    // pre-swizzled source chunk
  for (int k0 = 0; k0 < K; k0 += 64) {
#pragma unroll
    for (int r = 0; r < 4; ++r) {
      int row = wave * 32 + r * 8 + rsel;
      GLOAD16(&A16[(size_t)(m0 + row) * K + k0 + csel * 8], &sA[wave * 32 + r * 8][0]);
      GLOAD16(&B16[(size_t)(n0 + row) * K + k0 + csel * 8], &sB[wave * 32 + r * 8][0]);
    }
    __syncthreads();
#pragma unroll
    for (int kk = 0; kk < 2; ++kk) {
      int kc = kk * 4 + g;
      int cc = ((kc ^ (l15 & 7)) << 3);
      half8 af[4], bf[4];
#pragma unroll
      for (int mf = 0; mf < 4; ++mf) af[mf] = *(const half8*)&sA[wr * 64 + mf * 16 + l15][cc];
#pragma unroll
      for (int nf = 0; nf < 4; ++nf) bf[nf] = *(const half8*)&sB[wc * 64 + nf * 16 + l15][cc];
#pragma unroll
      for (int mf = 0; mf < 4; ++mf)
#pragma unroll
        for (int nf = 0; nf < 4; ++nf)
          acc[mf][nf] = MFMA16(af[mf], bf[nf], acc[mf][nf]);
    }
    __syncthreads();
  }
  int sec = n0 / 768;
  int nb = n0 - sec * 768;
#pragma unroll
  for (int mf = 0; mf < 4; ++mf)
#pragma unroll
    for (int nf = 0; nf < 4; ++nf)
#pragma unroll
      for (int r = 0; r < 4; ++r) {
        int m = m0 + wr * 64 + mf * 16 + (g << 2) + r;
        int n = nb + wc * 64 + nf * 16 + l15;
        int b = m >> 11, t = m & 2047;
        int h = n >> 6, d = n & 63;
        size_t idx = (((size_t)b * 12 + h) * 2048 + t) * 64 + d;
        _Float16 val = (_Float16)acc[mf][nf][r];
        if (sec == 0) qo[idx] = val;
        else if (sec == 1) ko[idx] = val;
        else v0o[idx] = val;
      }
}

// ---------------- v = (k (x) v0) @ Wv^T + bv  (fp16, deep-pipelined) ----------------
// 256 token-rows/block, 4 waves x 64 rows. i outer 8x8, B prefetched 1 full iter ahead.
__global__ __launch_bounds__(256, 3) void k_veins(
    const _Float16* __restrict__ kh, const _Float16* __restrict__ v0g,
    const _Float16* __restrict__ Wvh, const float* __restrict__ bv,
    _Float16* __restrict__ vout) {
  __shared__ _Float16 ks[256][72];  // 36 KB
  int tid = threadIdx.x, lane = tid & 63, wave = tid >> 6;
  int l15 = lane & 15, g = lane >> 4, g8 = g << 3;
  size_t row0 = (size_t)blockIdx.x * 256;
#pragma unroll
  for (int r = 0; r < 8; ++r) {
    int row = (tid >> 3) + r * 32;
    int c8 = (tid & 7) << 3;
    *(half8*)&ks[row][c8] = *(const half8*)&kh[(row0 + row) * 64 + c8];
  }
  half8 v0r[4][2];
#pragma unroll
  for (int mf = 0; mf < 4; ++mf) {
    size_t rb = (row0 + wave * 64 + mf * 16 + l15) * 64;
#pragma unroll
    for (int kk = 0; kk < 2; ++kk)
      v0r[mf][kk] = *(const half8*)&v0g[rb + kk * 32 + g8];
  }
  f32x4 acc[4][4];
#pragma unroll
  for (int a = 0; a < 4; ++a)
#pragma unroll
    for (int b = 0; b < 4; ++b) acc[a][b] = f32x4{0.f, 0.f, 0.f, 0.f};

  const _Float16* W0 = Wvh + (size_t)l15 * 4096 + g8;
  half8 b0[4], b1[4];
#pragma unroll
  for (int nf = 0; nf < 4; ++nf) {
    b0[nf] = *(const half8*)&W0[(size_t)nf * 65536];
    b1[nf] = *(const half8*)&W0[(size_t)nf * 65536 + 32];
  }
  __syncthreads();
  int r0 = wave * 64 + l15;
  for (int i8 = 0; i8 < 8; ++i8) {
    // 8 iterations of k per row, one ds_read_b128 each (rows r0, +16, +32, +48)
    half8 kr0 = *(const half8*)&ks[r0][i8 * 8];
    half8 kr1 = *(const half8*)&ks[r0 + 16][i8 * 8];
    half8 kr2 = *(const half8*)&ks[r0 + 32][i8 * 8];
    half8 kr3 = *(const half8*)&ks[r0 + 48][i8 * 8];
#pragma unroll
    for (int ii = 0; ii < 8; ++ii) {
      int i = i8 * 8 + ii;
      // prefetch BOTH halves of iteration i+1 before this iteration's MFMAs
      // (i=63 reads into the 8KB pad after Wv — harmless, never consumed)
      half8 n0[4], n1[4];
#pragma unroll
      for (int nf = 0; nf < 4; ++nf) {
        const _Float16* np = &W0[(size_t)nf * 65536 + (i + 1) * 64];
        n0[nf] = *(const half8*)np;
        n1[nf] = *(const half8*)(np + 32);
      }
      _Float16 kv0 = kr0[ii], kv1 = kr1[ii], kv2 = kr2[ii], kv3 = kr3[ii];
      {
        half8 a0 = v0r[0][0] * kv0, a1 = v0r[1][0] * kv1;
        half8 a2 = v0r[2][0] * kv2, a3 = v0r[3][0] * kv3;
#pragma unroll
        for (int nf = 0; nf < 4; ++nf) {
          acc[0][nf] = MFMA16(a0, b0[nf], acc[0][nf]);
          acc[1][nf] = MFMA16(a1, b0[nf], acc[1][nf]);
          acc[2][nf] = MFMA16(a2, b0[nf], acc[2][nf]);
          acc[3][nf] = MFMA16(a3, b0[nf], acc[3][nf]);
        }
      }
      {
        half8 a0 = v0r[0][1] * kv0, a1 = v0r[1][1] * kv1;
        half8 a2 = v0r[2][1] * kv2, a3 = v0r[3][1] * kv3;
#pragma unroll
        for (int nf = 0; nf < 4; ++nf) {
          acc[0][nf] = MFMA16(a0, b1[nf], acc[0][nf]);
          acc[1][nf] = MFMA16(a1, b1[nf], acc[1][nf]);
          acc[2][nf] = MFMA16(a2, b1[nf], acc[2][nf]);
          acc[3][nf] = MFMA16(a3, b1[nf], acc[3][nf]);
        }
      }
      // rotate prefetched fragments in (waitcnt lands here, after the 32 MFMAs)
#pragma unroll
      for (int nf = 0; nf < 4; ++nf) { b0[nf] = n0[nf]; b1[nf] = n1[nf]; }
    }
  }
#pragma unroll
  for (int mf = 0; mf < 4; ++mf)
#pragma unroll
    for (int nf = 0; nf < 4; ++nf) {
      int e = (nf << 4) + l15;
      float bve = bv[e];
#pragma unroll
      for (int r = 0; r < 4; ++r) {
        int row = wave * 64 + mf * 16 + (g << 2) + r;
        vout[(row0 + row) * 64 + e] = (_Float16)(acc[mf][nf][r] + bve);
      }
    }
}

// ---------------- segment sums -> Ks fp16 [bh][256][64], Vt fp16 [bh][64][256] ----------------
__global__ __launch_bounds__(256) void k_segments(
    const _Float16* __restrict__ kmat, const _Float16* __restrict__ vmat,
    _Float16* __restrict__ Ks, _Float16* __restrict__ Vt) {
  __shared__ float Ls[255][64];
  int bh = blockIdx.x, tid = threadIdx.x;
  size_t bh2048 = (size_t)bh * 2048;
  // ---- K ----
  for (int task = tid; task < 8192; task += 256) {
    int seg = task >> 6, d = task & 63;
    const _Float16* p = kmat + (bh2048 + seg * 16) * 64 + d;
    float s = 0.f;
#pragma unroll
    for (int u = 0; u < 16; ++u) s += (float)p[u * 64];
    Ls[seg][d] = s;
  }
  __syncthreads();
  {
    int bprev = 0, bcur = 128, cnt = 64;
    for (int lev = 1; lev < 8; ++lev) {
      for (int task = tid; task < cnt * 64; task += 256) {
        int i = task >> 6, d = task & 63;
        Ls[bcur + i][d] = Ls[bprev + 2 * i][d] + Ls[bprev + 2 * i + 1][d];
      }
      __syncthreads();
      bprev = bcur; bcur += cnt; cnt >>= 1;
    }
  }
  for (int task = tid; task < 16384; task += 256) {
    int seg = task >> 6;
    float v = (seg < 255) ? Ls[seg][task & 63] : 0.f;
    Ks[(size_t)bh * 16384 + task] = (_Float16)v;
  }
  __syncthreads();
  // ---- V ----
  for (int task = tid; task < 8192; task += 256) {
    int seg = task >> 6, d = task & 63;
    const _Float16* p = vmat + (bh2048 + seg * 16) * 64 + d;
    float s = 0.f;
#pragma unroll
    for (int u = 0; u < 16; ++u) s += (float)p[u * 64];
    Ls[seg][d] = s;
  }
  __syncthreads();
  {
    int bprev = 0, bcur = 128, cnt = 64;
    for (int lev = 1; lev < 8; ++lev) {
      for (int task = tid; task < cnt * 64; task += 256) {
        int i = task >> 6, d = task & 63;
        Ls[bcur + i][d] = Ls[bprev + 2 * i][d] + Ls[bprev + 2 * i + 1][d];
      }
      __syncthreads();
      bprev = bcur; bcur += cnt; cnt >>= 1;
    }
  }
  for (int task = tid; task < 16384; task += 256) {
    int d = task >> 8, seg = task & 255;
    float v = (seg < 255) ? Ls[seg][d] : 0.f;
    Vt[(size_t)bh * 16384 + task] = (_Float16)v;
  }
}

// ---------------- MFMA attention (fp16): block = (bh, 64-tok tile), 4 waves ----------------
__global__ __launch_bounds__(256) void k_attn2(
    const _Float16* __restrict__ qm, const _Float16* __restrict__ km,
    const _Float16* __restrict__ vm,
    const _Float16* __restrict__ Ks, const _Float16* __restrict__ Vt,
    _Float16* __restrict__ outp) {
  __shared__ __align__(16) _Float16 P[4][16][296];
  __shared__ __align__(16) _Float16 tK[4][16][72];
  __shared__ __align__(16) _Float16 tV[4][16][72];
  int tid = threadIdx.x, lane = tid & 63, wave = tid >> 6;
  int orig = blockIdx.y * 32 + blockIdx.x;
  int wg = (orig & 7) * 384 + (orig >> 3);  // XCD-chunked swizzle (3072 = 8*384)
  int tile = wg & 31, bh = wg >> 5;
  int t0 = tile * 64, tw0 = t0 + wave * 16;
  size_t bh2048 = (size_t)bh * 2048;
  int l15 = lane & 15, g = lane >> 4, g8 = g << 3;

  // per-wave tail prefixes (lane = d)
  {
    const _Float16* kp = km + (bh2048 + tw0) * 64 + lane;
    const _Float16* vp = vm + (bh2048 + tw0) * 64 + lane;
    float ka = 0.f, va = 0.f;
#pragma unroll
    for (int t = 0; t < 16; ++t) {
      ka += (float)kp[t * 64];
      va += (float)vp[t * 64];
      tK[wave][t][lane] = (_Float16)ka;
      tV[wave][t][lane] = (_Float16)va;
    }
  }
  // Q fragments
  half8 qf[2];
  {
    const _Float16* qp = qm + (bh2048 + tw0 + l15) * 64 + g8;
    qf[0] = *(const half8*)qp;
    qf[1] = *(const half8*)(qp + 32);
  }
  // validity masks
  unsigned mA = 0, mE = 0;
#pragma unroll
  for (int nf = 0; nf < 16; ++nf) {
    int seg = nf * 16 + l15;
    if (seg < 255) {
      int m = 256 - seg;
      int cl = 32 - __clz(m - 1);
      int lev = 8 - cl;
      int rdx = (seg - (256 - (256 >> lev)) + 1) * (16 << lev) - 1;
      if (rdx < tw0) mA |= 1u << nf;
      else if (rdx == tw0 + 15) mE |= 1u << nf;
    }
  }
  unsigned mAny = mA | mE;
  unsigned pmask = 0;
#pragma unroll
  for (int ks = 0; ks < 8; ++ks)
    if (__any((int)((mAny >> (2 * ks)) & 3u))) pmask |= 1u << ks;

  // ---- QK^T ----
  f32x4 acc[17];
#pragma unroll
  for (int i = 0; i < 17; ++i) acc[i] = f32x4{0.f, 0.f, 0.f, 0.f};
  const _Float16* KsB = Ks + (size_t)bh * 16384;
#pragma unroll
  for (int ks = 0; ks < 8; ++ks) {
    if ((pmask >> ks) & 1) {
      const _Float16* ph = KsB + (size_t)(ks * 32 + l15) * 64 + g8;
      half8 h00 = *(const half8*)ph;
      half8 h01 = *(const half8*)(ph + 32);
      half8 h10 = *(const half8*)(ph + 1024);
      half8 h11 = *(const half8*)(ph + 1056);
      acc[2 * ks] = MFMA16(qf[0], h00, acc[2 * ks]);
      acc[2 * ks] = MFMA16(qf[1], h01, acc[2 * ks]);
      acc[2 * ks + 1] = MFMA16(qf[0], h10, acc[2 * ks + 1]);
      acc[2 * ks + 1] = MFMA16(qf[1], h11, acc[2 * ks + 1]);
    }
  }
  {  // tail fragment (nf=16)
    const _Float16* tp = &tK[wave][l15][g8];
    half8 t0f = *(const half8*)tp;
    half8 t1f = *(const half8*)(tp + 32);
    acc[16] = MFMA16(qf[0], t0f, acc[16]);
    acc[16] = MFMA16(qf[1], t1f, acc[16]);
  }

  // ---- softmax (f32) ----
  const float scale = 0.125f;
  float mx[4], sm[4], et[4];
#pragma unroll
  for (int r = 0; r < 4; ++r) {
    int tr = g * 4 + r;
    mx[r] = (l15 == tr) ? acc[16][r] * scale : -3.0e38f;
  }
#pragma unroll
  for (int nf = 0; nf < 16; ++nf) {
    bool bA = (mA >> nf) & 1, bE = (mE >> nf) & 1;
#pragma unroll
    for (int r = 0; r < 4; ++r) {
      bool u = bA || (bE && g == 3 && r == 3);
      if (u) mx[r] = fmaxf(mx[r], acc[nf][r] * scale);
    }
  }
#pragma unroll
  for (int off = 1; off < 16; off <<= 1)
#pragma unroll
    for (int r = 0; r < 4; ++r) mx[r] = fmaxf(mx[r], __shfl_xor(mx[r], off));
#pragma unroll
  for (int r = 0; r < 4; ++r) {
    int tr = g * 4 + r;
    et[r] = (l15 == tr) ? __expf(acc[16][r] * scale - mx[r]) : 0.f;
    sm[r] = et[r];
  }
#pragma unroll
  for (int ks = 0; ks < 8; ++ks) {
    if ((pmask >> ks) & 1) {
#pragma unroll
      for (int f = 0; f < 2; ++f) {
        int nf = 2 * ks + f;
        bool bA = (mA >> nf) & 1, bE = (mE >> nf) & 1;
#pragma unroll
        for (int r = 0; r < 4; ++r) {
          bool u = bA || (bE && g == 3 && r == 3);
          float e = u ? __expf(acc[nf][r] * scale - mx[r]) : 0.f;
          acc[nf][r] = e;
          sm[r] += e;
        }
      }
    }
  }
#pragma unroll
  for (int off = 1; off < 16; off <<= 1)
#pragma unroll
    for (int r = 0; r < 4; ++r) sm[r] += __shfl_xor(sm[r], off);
  float inv[4];
#pragma unroll
  for (int r = 0; r < 4; ++r) inv[r] = 1.f / sm[r];

  // ---- P writes (per-wave LDS) ----
  half8 zz = {};
  *(half8*)&P[wave][lane >> 2][256 + (lane & 3) * 8] = zz;
#pragma unroll
  for (int nf = 0; nf < 16; ++nf)
#pragma unroll
    for (int r = 0; r < 4; ++r)
      P[wave][g * 4 + r][nf * 16 + l15] = (_Float16)(acc[nf][r] * inv[r]);
#pragma unroll
  for (int r = 0; r < 4; ++r)
    if (l15 == g * 4 + r) P[wave][l15][256 + l15] = (_Float16)(et[r] * inv[r]);

  // ---- PV ----
  f32x4 oa[4];
#pragma unroll
  for (int i = 0; i < 4; ++i) oa[i] = f32x4{0.f, 0.f, 0.f, 0.f};
  const _Float16* VB = Vt + (size_t)bh * 16384;
#pragma unroll
  for (int ks = 0; ks < 8; ++ks) {
    if ((pmask >> ks) & 1) {
      half8 pa = *(const half8*)&P[wave][l15][ks * 32 + g8];
#pragma unroll
      for (int n2 = 0; n2 < 4; ++n2) {
        half8 vb = *(const half8*)(VB + (size_t)(n2 * 16 + l15) * 256 + ks * 32 + g8);
        oa[n2] = MFMA16(pa, vb, oa[n2]);
      }
    }
  }
  {  // tail k-step
    half8 pa = *(const half8*)&P[wave][l15][256 + g8];
    int jb = (g & 1) * 8;
#pragma unroll
    for (int n2 = 0; n2 < 4; ++n2) {
      half8 vt;
#pragma unroll
      for (int jj = 0; jj < 8; ++jj) vt[jj] = tV[wave][jb + jj][n2 * 16 + l15];
      oa[n2] = MFMA16(pa, vt, oa[n2]);
    }
  }
  // ---- output ----
  int b = bh / 12, h = bh - b * 12;
  size_t obase = ((size_t)b * 2048 + tw0) * 768 + h * 64;
#pragma unroll
  for (int n2 = 0; n2 < 4; ++n2)
#pragma unroll
    for (int r = 0; r < 4; ++r)
      outp[obase + (size_t)(g * 4 + r) * 768 + n2 * 16 + l15] = (_Float16)oa[n2][r];
}

// ---------------- proj GEMM: d_out = out_pre @ Wproj^T (fp16, gload staging) ----------------
__global__ __launch_bounds__(256, 3) void k_gemm_proj(
    const _Float16* __restrict__ A16, const _Float16* __restrict__ B16,
    float* __restrict__ C) {
  __shared__ _Float16 sA[128][64], sB[128][64];
  const int K = 768;
  int tid = threadIdx.x, lane = tid & 63, wave = tid >> 6;
  int l15 = lane & 15, g = lane >> 4;
  int wr = wave >> 1, wc = wave & 1;
  int n0 = blockIdx.x * 128, m0 = blockIdx.y * 128;
  f32x4 acc[4][4];
#pragma unroll
  for (int a = 0; a < 4; ++a)
#pragma unroll
    for (int b = 0; b < 4; ++b) acc[a][b] = f32x4{0.f, 0.f, 0.f, 0.f};
  int rsel = lane >> 3;
  int csel = (lane & 7) ^ rsel;
  for (int k0 = 0; k0 < K; k0 += 64) {
#pragma unroll
    for (int r = 0; r < 4; ++r) {
      int row = wave * 32 + r * 8 + rsel;
      GLOAD16(&A16[(size_t)(m0 + row) * K + k0 + csel * 8], &sA[wave * 32 + r * 8][0]);
      GLOAD16(&B16[(size_t)(n0 + row) * K + k0 + csel * 8], &sB[wave * 32 + r * 8][0]);
    }
    __syncthreads();
#pragma unroll
    for (int kk = 0; kk < 2; ++kk) {
      int kc = kk * 4 + g;
      int cc = ((kc ^ (l15 & 7)) << 3);
      half8 af[4], bf[4];
#pragma unroll
      for (int mf = 0; mf < 4; ++mf) af[mf] = *(const half8*)&sA[wr * 64 + mf * 16 + l15][cc];
#pragma unroll
      for (int nf = 0; nf < 4; ++nf) bf[nf] = *(const half8*)&sB[wc * 64 + nf * 16 + l15][cc];
#pragma unroll
      for (int mf = 0; mf < 4; ++mf)
#pragma unroll
        for (int nf = 0; nf < 4; ++nf)
          acc[mf][nf] = MFMA16(af[mf], bf[nf], acc[mf][nf]);
    }
    __syncthreads();
  }
#pragma unroll
  for (int mf = 0; mf < 4; ++mf)
#pragma unroll
    for (int nf = 0; nf < 4; ++nf)
#pragma unroll
      for (int r = 0; r < 4; ++r) {
        int m = m0 + wr * 64 + mf * 16 + (g << 2) + r;
        int n = n0 + wc * 64 + nf * 16 + l15;
        C[(size_t)m * 768 + n] = acc[mf][nf][r];
      }
}

// ---------------- host launch ----------------
extern "C" void kernel_launch(void* const* d_in, const int* in_sizes, int n_in,
                              void* d_out, int out_size, void* d_ws, size_t ws_size,
                              hipStream_t stream) {
  const float* x = (const float*)d_in[0];
  const float* Wqkv = (const float*)d_in[1];
  const float* Wproj = (const float*)d_in[2];
  const float* Wv = (const float*)d_in[3];
  const float* bv = (const float*)d_in[4];
  float* out = (float*)d_out;
  char* ws = (char*)d_ws;
  size_t off = 0;
  auto alloc = [&](size_t bytes) -> void* {
    void* p = (void*)(ws + off);
    off += (bytes + 255) & ~(size_t)255;
    return p;
  };
  _Float16* x16  = (_Float16*)alloc(12582912ull * 2);
  _Float16* wq16 = (_Float16*)alloc(1769472ull * 2);
  _Float16* wv16 = (_Float16*)alloc(262144ull * 2 + 8192);  // +8KB pad for i=63 prefetch
  _Float16* wp16 = (_Float16*)alloc(589824ull * 2);
  _Float16* q16  = (_Float16*)alloc(12582912ull * 2);
  _Float16* k16  = (_Float16*)alloc(12582912ull * 2);
  _Float16* v016 = (_Float16*)alloc(12582912ull * 2);
  _Float16* vm16 = (_Float16*)alloc(12582912ull * 2);
  _Float16* Ks   = (_Float16*)alloc(1572864ull * 2);
  _Float16* Vt   = (_Float16*)alloc(1572864ull * 2);
  _Float16* outp = (_Float16*)alloc(12582912ull * 2);

  k_cast16<<<dim3(12288), dim3(256), 0, stream>>>(x, x16, 3145728);
  k_cast16<<<dim3(1728), dim3(256), 0, stream>>>(Wqkv, wq16, 442368);
  k_cast16<<<dim3(256), dim3(256), 0, stream>>>(Wv, wv16, 65536);
  k_cast16<<<dim3(576), dim3(256), 0, stream>>>(Wproj, wp16, 147456);
  k_gemm_qkv<<<dim3(18, 128), dim3(256), 0, stream>>>(x16, wq16, q16, k16, v016);
  k_veins<<<dim3(768), dim3(256), 0, stream>>>(k16, v016, wv16, bv, vm16);
  k_segments<<<dim3(96), dim3(256), 0, stream>>>(k16, vm16, Ks, Vt);
  k_attn2<<<dim3(32, 96), dim3(256), 0, stream>>>(q16, k16, vm16, Ks, Vt, outp);
  k_gemm_proj<<<dim3(6, 128), dim3(256), 0, stream>>>(outp, wp16, out);
}

// Round 7
// 356.203 us; speedup vs baseline: 1.3150x; 1.3150x over previous
//
#include <hip/hip_runtime.h>

// FixSetLinearAttention: B=8 T=2048 C=768 NH=12 hs=64 Lmin=16, 255 segments + tail.
// R7: k_veins was L2-BW-bound (each wave streamed all 512KB of Wv; 4x redundant).
// Now the 8KB/iteration B-tile is staged ONCE per block into LDS via global_load_lds
// (pre-swizzled source, XOR-chunk layout), double-buffered, 1 barrier/iter.
// Rest identical to R6 (all-fp16, 468us, absmax 0.125).

typedef float  f32x4  __attribute__((ext_vector_type(4)));
typedef _Float16 half8 __attribute__((ext_vector_type(8)));
typedef _Float16 half4 __attribute__((ext_vector_type(4)));

#define DEV __device__ __forceinline__
#define MFMA16(a, b, c) __builtin_amdgcn_mfma_f32_16x16x32_f16((a), (b), (c), 0, 0, 0)
#define GLOAD16(gp, lp)                                                  \
  __builtin_amdgcn_global_load_lds(                                      \
      (const __attribute__((address_space(1))) unsigned int*)(gp),       \
      (__attribute__((address_space(3))) unsigned int*)(lp), 16, 0, 0)

// ---------------- prep: f32 -> fp16 ----------------
__global__ __launch_bounds__(256) void k_cast16(const float* __restrict__ in,
                                                _Float16* __restrict__ outh, int n4) {
  int i = blockIdx.x * 256 + threadIdx.x;
  if (i >= n4) return;
  f32x4 v = ((const f32x4*)in)[i];
  half4 o;
#pragma unroll
  for (int c = 0; c < 4; ++c) o[c] = (_Float16)v[c];
  ((half4*)outh)[i] = o;
}

// ---------------- qkv GEMM: C = A @ B^T, fp16 single pass ----------------
__global__ __launch_bounds__(256, 3) void k_gemm_qkv(
    const _Float16* __restrict__ A16, const _Float16* __restrict__ B16,
    _Float16* __restrict__ qo, _Float16* __restrict__ ko, _Float16* __restrict__ v0o) {
  __shared__ _Float16 sA[128][64], sB[128][64];
  const int K = 768;
  int tid = threadIdx.x, lane = tid & 63, wave = tid >> 6;
  int l15 = lane & 15, g = lane >> 4;
  int wr = wave >> 1, wc = wave & 1;
  int n0 = blockIdx.x * 128, m0 = blockIdx.y * 128;
  f32x4 acc[4][4];
#pragma unroll
  for (int a = 0; a < 4; ++a)
#pragma unroll
    for (int b = 0; b < 4; ++b) acc[a][b] = f32x4{0.f, 0.f, 0.f, 0.f};
  int rsel = lane >> 3;            // row within 8-row group; row&7 == rsel
  int csel = (lane & 7) ^ rsel;    // pre-swizzled source chunk
  for (int k0 = 0; k0 < K; k0 += 64) {
#pragma unroll
    for (int r = 0; r < 4; ++r) {
      int row = wave * 32 + r * 8 + rsel;
      GLOAD16(&A16[(size_t)(m0 + row) * K + k0 + csel * 8], &sA[wave * 32 + r * 8][0]);
      GLOAD16(&B16[(size_t)(n0 + row) * K + k0 + csel * 8], &sB[wave * 32 + r * 8][0]);
    }
    __syncthreads();
#pragma unroll
    for (int kk = 0; kk < 2; ++kk) {
      int kc = kk * 4 + g;
      int cc = ((kc ^ (l15 & 7)) << 3);
      half8 af[4], bf[4];
#pragma unroll
      for (int mf = 0; mf < 4; ++mf) af[mf] = *(const half8*)&sA[wr * 64 + mf * 16 + l15][cc];
#pragma unroll
      for (int nf = 0; nf < 4; ++nf) bf[nf] = *(const half8*)&sB[wc * 64 + nf * 16 + l15][cc];
#pragma unroll
      for (int mf = 0; mf < 4; ++mf)
#pragma unroll
        for (int nf = 0; nf < 4; ++nf)
          acc[mf][nf] = MFMA16(af[mf], bf[nf], acc[mf][nf]);
    }
    __syncthreads();
  }
  int sec = n0 / 768;
  int nb = n0 - sec * 768;
#pragma unroll
  for (int mf = 0; mf < 4; ++mf)
#pragma unroll
    for (int nf = 0; nf < 4; ++nf)
#pragma unroll
      for (int r = 0; r < 4; ++r) {
        int m = m0 + wr * 64 + mf * 16 + (g << 2) + r;
        int n = nb + wc * 64 + nf * 16 + l15;
        int b = m >> 11, t = m & 2047;
        int h = n >> 6, d = n & 63;
        size_t idx = (((size_t)b * 12 + h) * 2048 + t) * 64 + d;
        _Float16 val = (_Float16)acc[mf][nf][r];
        if (sec == 0) qo[idx] = val;
        else if (sec == 1) ko[idx] = val;
        else v0o[idx] = val;
      }
}

// ---------------- v = (k (x) v0) @ Wv^T + bv  (fp16, LDS-shared B tiles) ----------------
// 256 token-rows/block, 4 waves x 64 rows. Per-iteration 8KB B-tile staged once per
// block (global_load_lds, swizzled), double-buffered; 4 waves share it.
__global__ __launch_bounds__(256, 3) void k_veins(
    const _Float16* __restrict__ kh, const _Float16* __restrict__ v0g,
    const _Float16* __restrict__ Wvh, const float* __restrict__ bv,
    _Float16* __restrict__ vout) {
  __shared__ _Float16 ks[256][72];     // 36 KB
  __shared__ _Float16 sB[2][64][64];   // 16 KB, XOR-chunk swizzled
  int tid = threadIdx.x, lane = tid & 63, wave = tid >> 6;
  int l15 = lane & 15, g = lane >> 4, g8 = g << 3;
  size_t row0 = (size_t)blockIdx.x * 256;

  // stage B tile for iteration i into buffer b: linear LDS dest, pre-swizzled source.
  // slot = h*256 + wave*64 + lane -> row e = slot>>3 (0..63), chunk_dst = lane&7,
  // chunk_src = chunk_dst ^ (row&7) = (lane&7) ^ (lane>>3).
  int srow_lo = wave * 8 + (lane >> 3);
  int scsrc = (lane & 7) ^ (lane >> 3);
  auto STAGE = [&](int b, int i) {
#pragma unroll
    for (int h = 0; h < 2; ++h) {
      GLOAD16(&Wvh[(size_t)(h * 32 + srow_lo) * 4096 + i * 64 + (scsrc << 3)],
              ((_Float16*)sB) + (size_t)b * 4096 + (h * 256 + wave * 64) * 8);
    }
  };

  // stage k tile (vector copies)
#pragma unroll
  for (int r = 0; r < 8; ++r) {
    int row = (tid >> 3) + r * 32;
    int c8 = (tid & 7) << 3;
    *(half8*)&ks[row][c8] = *(const half8*)&kh[(row0 + row) * 64 + c8];
  }
  // v0 fragments resident in regs: [mf][kk]
  half8 v0r[4][2];
#pragma unroll
  for (int mf = 0; mf < 4; ++mf) {
    size_t rb = (row0 + wave * 64 + mf * 16 + l15) * 64;
#pragma unroll
    for (int kk = 0; kk < 2; ++kk)
      v0r[mf][kk] = *(const half8*)&v0g[rb + kk * 32 + g8];
  }
  f32x4 acc[4][4];
#pragma unroll
  for (int a = 0; a < 4; ++a)
#pragma unroll
    for (int b = 0; b < 4; ++b) acc[a][b] = f32x4{0.f, 0.f, 0.f, 0.f};

  STAGE(0, 0);
  __syncthreads();  // drains vmcnt: buf0 ready; ks ready
  int r0 = wave * 64 + l15;
  for (int i8 = 0; i8 < 8; ++i8) {
    half8 kr0 = *(const half8*)&ks[r0][i8 * 8];
    half8 kr1 = *(const half8*)&ks[r0 + 16][i8 * 8];
    half8 kr2 = *(const half8*)&ks[r0 + 32][i8 * 8];
    half8 kr3 = *(const half8*)&ks[r0 + 48][i8 * 8];
#pragma unroll
    for (int ii = 0; ii < 8; ++ii) {
      int i = i8 * 8 + ii;
      int cur = i & 1;
      if (i < 63) STAGE(cur ^ 1, i + 1);  // async; lands before next barrier
      // B fragments from shared tile (XOR-chunk read, conflict-free pattern)
      half8 b0[4], b1[4];
#pragma unroll
      for (int nf = 0; nf < 4; ++nf) {
        b0[nf] = *(const half8*)&sB[cur][nf * 16 + l15][((g ^ (l15 & 7)) << 3)];
        b1[nf] = *(const half8*)&sB[cur][nf * 16 + l15][(((4 + g) ^ (l15 & 7)) << 3)];
      }
      _Float16 kv0 = kr0[ii], kv1 = kr1[ii], kv2 = kr2[ii], kv3 = kr3[ii];
      {
        half8 a0 = v0r[0][0] * kv0, a1 = v0r[1][0] * kv1;
        half8 a2 = v0r[2][0] * kv2, a3 = v0r[3][0] * kv3;
#pragma unroll
        for (int nf = 0; nf < 4; ++nf) {
          acc[0][nf] = MFMA16(a0, b0[nf], acc[0][nf]);
          acc[1][nf] = MFMA16(a1, b0[nf], acc[1][nf]);
          acc[2][nf] = MFMA16(a2, b0[nf], acc[2][nf]);
          acc[3][nf] = MFMA16(a3, b0[nf], acc[3][nf]);
        }
      }
      {
        half8 a0 = v0r[0][1] * kv0, a1 = v0r[1][1] * kv1;
        half8 a2 = v0r[2][1] * kv2, a3 = v0r[3][1] * kv3;
#pragma unroll
        for (int nf = 0; nf < 4; ++nf) {
          acc[0][nf] = MFMA16(a0, b1[nf], acc[0][nf]);
          acc[1][nf] = MFMA16(a1, b1[nf], acc[1][nf]);
          acc[2][nf] = MFMA16(a2, b1[nf], acc[2][nf]);
          acc[3][nf] = MFMA16(a3, b1[nf], acc[3][nf]);
        }
      }
      // barrier: (a) all reads of buf[cur] done before it's restaged at i+1,
      // (b) implicit vmcnt(0) drain ensures buf[cur^1] staged for i+1.
      __syncthreads();
    }
  }
#pragma unroll
  for (int mf = 0; mf < 4; ++mf)
#pragma unroll
    for (int nf = 0; nf < 4; ++nf) {
      int e = (nf << 4) + l15;
      float bve = bv[e];
#pragma unroll
      for (int r = 0; r < 4; ++r) {
        int row = wave * 64 + mf * 16 + (g << 2) + r;
        vout[(row0 + row) * 64 + e] = (_Float16)(acc[mf][nf][r] + bve);
      }
    }
}

// ---------------- segment sums -> Ks fp16 [bh][256][64], Vt fp16 [bh][64][256] ----------------
__global__ __launch_bounds__(256) void k_segments(
    const _Float16* __restrict__ kmat, const _Float16* __restrict__ vmat,
    _Float16* __restrict__ Ks, _Float16* __restrict__ Vt) {
  __shared__ float Ls[255][64];
  int bh = blockIdx.x, tid = threadIdx.x;
  size_t bh2048 = (size_t)bh * 2048;
  // ---- K ----
  for (int task = tid; task < 8192; task += 256) {
    int seg = task >> 6, d = task & 63;
    const _Float16* p = kmat + (bh2048 + seg * 16) * 64 + d;
    float s = 0.f;
#pragma unroll
    for (int u = 0; u < 16; ++u) s += (float)p[u * 64];
    Ls[seg][d] = s;
  }
  __syncthreads();
  {
    int bprev = 0, bcur = 128, cnt = 64;
    for (int lev = 1; lev < 8; ++lev) {
      for (int task = tid; task < cnt * 64; task += 256) {
        int i = task >> 6, d = task & 63;
        Ls[bcur + i][d] = Ls[bprev + 2 * i][d] + Ls[bprev + 2 * i + 1][d];
      }
      __syncthreads();
      bprev = bcur; bcur += cnt; cnt >>= 1;
    }
  }
  for (int task = tid; task < 16384; task += 256) {
    int seg = task >> 6;
    float v = (seg < 255) ? Ls[seg][task & 63] : 0.f;
    Ks[(size_t)bh * 16384 + task] = (_Float16)v;
  }
  __syncthreads();
  // ---- V ----
  for (int task = tid; task < 8192; task += 256) {
    int seg = task >> 6, d = task & 63;
    const _Float16* p = vmat + (bh2048 + seg * 16) * 64 + d;
    float s = 0.f;
#pragma unroll
    for (int u = 0; u < 16; ++u) s += (float)p[u * 64];
    Ls[seg][d] = s;
  }
  __syncthreads();
  {
    int bprev = 0, bcur = 128, cnt = 64;
    for (int lev = 1; lev < 8; ++lev) {
      for (int task = tid; task < cnt * 64; task += 256) {
        int i = task >> 6, d = task & 63;
        Ls[bcur + i][d] = Ls[bprev + 2 * i][d] + Ls[bprev + 2 * i + 1][d];
      }
      __syncthreads();
      bprev = bcur; bcur += cnt; cnt >>= 1;
    }
  }
  for (int task = tid; task < 16384; task += 256) {
    int d = task >> 8, seg = task & 255;
    float v = (seg < 255) ? Ls[seg][d] : 0.f;
    Vt[(size_t)bh * 16384 + task] = (_Float16)v;
  }
}

// ---------------- MFMA attention (fp16): block = (bh, 64-tok tile), 4 waves ----------------
__global__ __launch_bounds__(256) void k_attn2(
    const _Float16* __restrict__ qm, const _Float16* __restrict__ km,
    const _Float16* __restrict__ vm,
    const _Float16* __restrict__ Ks, const _Float16* __restrict__ Vt,
    _Float16* __restrict__ outp) {
  __shared__ __align__(16) _Float16 P[4][16][296];
  __shared__ __align__(16) _Float16 tK[4][16][72];
  __shared__ __align__(16) _Float16 tV[4][16][72];
  int tid = threadIdx.x, lane = tid & 63, wave = tid >> 6;
  int orig = blockIdx.y * 32 + blockIdx.x;
  int wg = (orig & 7) * 384 + (orig >> 3);  // XCD-chunked swizzle (3072 = 8*384)
  int tile = wg & 31, bh = wg >> 5;
  int t0 = tile * 64, tw0 = t0 + wave * 16;
  size_t bh2048 = (size_t)bh * 2048;
  int l15 = lane & 15, g = lane >> 4, g8 = g << 3;

  // per-wave tail prefixes (lane = d)
  {
    const _Float16* kp = km + (bh2048 + tw0) * 64 + lane;
    const _Float16* vp = vm + (bh2048 + tw0) * 64 + lane;
    float ka = 0.f, va = 0.f;
#pragma unroll
    for (int t = 0; t < 16; ++t) {
      ka += (float)kp[t * 64];
      va += (float)vp[t * 64];
      tK[wave][t][lane] = (_Float16)ka;
      tV[wave][t][lane] = (_Float16)va;
    }
  }
  // Q fragments
  half8 qf[2];
  {
    const _Float16* qp = qm + (bh2048 + tw0 + l15) * 64 + g8;
    qf[0] = *(const half8*)qp;
    qf[1] = *(const half8*)(qp + 32);
  }
  // validity masks
  unsigned mA = 0, mE = 0;
#pragma unroll
  for (int nf = 0; nf < 16; ++nf) {
    int seg = nf * 16 + l15;
    if (seg < 255) {
      int m = 256 - seg;
      int cl = 32 - __clz(m - 1);
      int lev = 8 - cl;
      int rdx = (seg - (256 - (256 >> lev)) + 1) * (16 << lev) - 1;
      if (rdx < tw0) mA |= 1u << nf;
      else if (rdx == tw0 + 15) mE |= 1u << nf;
    }
  }
  unsigned mAny = mA | mE;
  unsigned pmask = 0;
#pragma unroll
  for (int ks = 0; ks < 8; ++ks)
    if (__any((int)((mAny >> (2 * ks)) & 3u))) pmask |= 1u << ks;

  // ---- QK^T ----
  f32x4 acc[17];
#pragma unroll
  for (int i = 0; i < 17; ++i) acc[i] = f32x4{0.f, 0.f, 0.f, 0.f};
  const _Float16* KsB = Ks + (size_t)bh * 16384;
#pragma unroll
  for (int ks = 0; ks < 8; ++ks) {
    if ((pmask >> ks) & 1) {
      const _Float16* ph = KsB + (size_t)(ks * 32 + l15) * 64 + g8;
      half8 h00 = *(const half8*)ph;
      half8 h01 = *(const half8*)(ph + 32);
      half8 h10 = *(const half8*)(ph + 1024);
      half8 h11 = *(const half8*)(ph + 1056);
      acc[2 * ks] = MFMA16(qf[0], h00, acc[2 * ks]);
      acc[2 * ks] = MFMA16(qf[1], h01, acc[2 * ks]);
      acc[2 * ks + 1] = MFMA16(qf[0], h10, acc[2 * ks + 1]);
      acc[2 * ks + 1] = MFMA16(qf[1], h11, acc[2 * ks + 1]);
    }
  }
  {  // tail fragment (nf=16)
    const _Float16* tp = &tK[wave][l15][g8];
    half8 t0f = *(const half8*)tp;
    half8 t1f = *(const half8*)(tp + 32);
    acc[16] = MFMA16(qf[0], t0f, acc[16]);
    acc[16] = MFMA16(qf[1], t1f, acc[16]);
  }

  // ---- softmax (f32) ----
  const float scale = 0.125f;
  float mx[4], sm[4], et[4];
#pragma unroll
  for (int r = 0; r < 4; ++r) {
    int tr = g * 4 + r;
    mx[r] = (l15 == tr) ? acc[16][r] * scale : -3.0e38f;
  }
#pragma unroll
  for (int nf = 0; nf < 16; ++nf) {
    bool bA = (mA >> nf) & 1, bE = (mE >> nf) & 1;
#pragma unroll
    for (int r = 0; r < 4; ++r) {
      bool u = bA || (bE && g == 3 && r == 3);
      if (u) mx[r] = fmaxf(mx[r], acc[nf][r] * scale);
    }
  }
#pragma unroll
  for (int off = 1; off < 16; off <<= 1)
#pragma unroll
    for (int r = 0; r < 4; ++r) mx[r] = fmaxf(mx[r], __shfl_xor(mx[r], off));
#pragma unroll
  for (int r = 0; r < 4; ++r) {
    int tr = g * 4 + r;
    et[r] = (l15 == tr) ? __expf(acc[16][r] * scale - mx[r]) : 0.f;
    sm[r] = et[r];
  }
#pragma unroll
  for (int ks = 0; ks < 8; ++ks) {
    if ((pmask >> ks) & 1) {
#pragma unroll
      for (int f = 0; f < 2; ++f) {
        int nf = 2 * ks + f;
        bool bA = (mA >> nf) & 1, bE = (mE >> nf) & 1;
#pragma unroll
        for (int r = 0; r < 4; ++r) {
          bool u = bA || (bE && g == 3 && r == 3);
          float e = u ? __expf(acc[nf][r] * scale - mx[r]) : 0.f;
          acc[nf][r] = e;
          sm[r] += e;
        }
      }
    }
  }
#pragma unroll
  for (int off = 1; off < 16; off <<= 1)
#pragma unroll
    for (int r = 0; r < 4; ++r) sm[r] += __shfl_xor(sm[r], off);
  float inv[4];
#pragma unroll
  for (int r = 0; r < 4; ++r) inv[r] = 1.f / sm[r];

  // ---- P writes (per-wave LDS) ----
  half8 zz = {};
  *(half8*)&P[wave][lane >> 2][256 + (lane & 3) * 8] = zz;
#pragma unroll
  for (int nf = 0; nf < 16; ++nf)
#pragma unroll
    for (int r = 0; r < 4; ++r)
      P[wave][g * 4 + r][nf * 16 + l15] = (_Float16)(acc[nf][r] * inv[r]);
#pragma unroll
  for (int r = 0; r < 4; ++r)
    if (l15 == g * 4 + r) P[wave][l15][256 + l15] = (_Float16)(et[r] * inv[r]);

  // ---- PV ----
  f32x4 oa[4];
#pragma unroll
  for (int i = 0; i < 4; ++i) oa[i] = f32x4{0.f, 0.f, 0.f, 0.f};
  const _Float16* VB = Vt + (size_t)bh * 16384;
#pragma unroll
  for (int ks = 0; ks < 8; ++ks) {
    if ((pmask >> ks) & 1) {
      half8 pa = *(const half8*)&P[wave][l15][ks * 32 + g8];
#pragma unroll
      for (int n2 = 0; n2 < 4; ++n2) {
        half8 vb = *(const half8*)(VB + (size_t)(n2 * 16 + l15) * 256 + ks * 32 + g8);
        oa[n2] = MFMA16(pa, vb, oa[n2]);
      }
    }
  }
  {  // tail k-step
    half8 pa = *(const half8*)&P[wave][l15][256 + g8];
    int jb = (g & 1) * 8;
#pragma unroll
    for (int n2 = 0; n2 < 4; ++n2) {
      half8 vt;
#pragma unroll
      for (int jj = 0; jj < 8; ++jj) vt[jj] = tV[wave][jb + jj][n2 * 16 + l15];
      oa[n2] = MFMA16(pa, vt, oa[n2]);
    }
  }
  // ---- output ----
  int b = bh / 12, h = bh - b * 12;
  size_t obase = ((size_t)b * 2048 + tw0) * 768 + h * 64;
#pragma unroll
  for (int n2 = 0; n2 < 4; ++n2)
#pragma unroll
    for (int r = 0; r < 4; ++r)
      outp[obase + (size_t)(g * 4 + r) * 768 + n2 * 16 + l15] = (_Float16)oa[n2][r];
}

// ---------------- proj GEMM: d_out = out_pre @ Wproj^T (fp16, gload staging) ----------------
__global__ __launch_bounds__(256, 3) void k_gemm_proj(
    const _Float16* __restrict__ A16, const _Float16* __restrict__ B16,
    float* __restrict__ C) {
  __shared__ _Float16 sA[128][64], sB[128][64];
  const int K = 768;
  int tid = threadIdx.x, lane = tid & 63, wave = tid >> 6;
  int l15 = lane & 15, g = lane >> 4;
  int wr = wave >> 1, wc = wave & 1;
  int n0 = blockIdx.x * 128, m0 = blockIdx.y * 128;
  f32x4 acc[4][4];
#pragma unroll
  for (int a = 0; a < 4; ++a)
#pragma unroll
    for (int b = 0; b < 4; ++b) acc[a][b] = f32x4{0.f, 0.f, 0.f, 0.f};
  int rsel = lane >> 3;
  int csel = (lane & 7) ^ rsel;
  for (int k0 = 0; k0 < K; k0 += 64) {
#pragma unroll
    for (int r = 0; r < 4; ++r) {
      int row = wave * 32 + r * 8 + rsel;
      GLOAD16(&A16[(size_t)(m0 + row) * K + k0 + csel * 8], &sA[wave * 32 + r * 8][0]);
      GLOAD16(&B16[(size_t)(n0 + row) * K + k0 + csel * 8], &sB[wave * 32 + r * 8][0]);
    }
    __syncthreads();
#pragma unroll
    for (int kk = 0; kk < 2; ++kk) {
      int kc = kk * 4 + g;
      int cc = ((kc ^ (l15 & 7)) << 3);
      half8 af[4], bf[4];
#pragma unroll
      for (int mf = 0; mf < 4; ++mf) af[mf] = *(const half8*)&sA[wr * 64 + mf * 16 + l15][cc];
#pragma unroll
      for (int nf = 0; nf < 4; ++nf) bf[nf] = *(const half8*)&sB[wc * 64 + nf * 16 + l15][cc];
#pragma unroll
      for (int mf = 0; mf < 4; ++mf)
#pragma unroll
        for (int nf = 0; nf < 4; ++nf)
          acc[mf][nf] = MFMA16(af[mf], bf[nf], acc[mf][nf]);
    }
    __syncthreads();
  }
#pragma unroll
  for (int mf = 0; mf < 4; ++mf)
#pragma unroll
    for (int nf = 0; nf < 4; ++nf)
#pragma unroll
      for (int r = 0; r < 4; ++r) {
        int m = m0 + wr * 64 + mf * 16 + (g << 2) + r;
        int n = n0 + wc * 64 + nf * 16 + l15;
        C[(size_t)m * 768 + n] = acc[mf][nf][r];
      }
}

// ---------------- host launch ----------------
extern "C" void kernel_launch(void* const* d_in, const int* in_sizes, int n_in,
                              void* d_out, int out_size, void* d_ws, size_t ws_size,
                              hipStream_t stream) {
  const float* x = (const float*)d_in[0];
  const float* Wqkv = (const float*)d_in[1];
  const float* Wproj = (const float*)d_in[2];
  const float* Wv = (const float*)d_in[3];
  const float* bv = (const float*)d_in[4];
  float* out = (float*)d_out;
  char* ws = (char*)d_ws;
  size_t off = 0;
  auto alloc = [&](size_t bytes) -> void* {
    void* p = (void*)(ws + off);
    off += (bytes + 255) & ~(size_t)255;
    return p;
  };
  _Float16* x16  = (_Float16*)alloc(12582912ull * 2);
  _Float16* wq16 = (_Float16*)alloc(1769472ull * 2);
  _Float16* wv16 = (_Float16*)alloc(262144ull * 2 + 8192);
  _Float16* wp16 = (_Float16*)alloc(589824ull * 2);
  _Float16* q16  = (_Float16*)alloc(12582912ull * 2);
  _Float16* k16  = (_Float16*)alloc(12582912ull * 2);
  _Float16* v016 = (_Float16*)alloc(12582912ull * 2);
  _Float16* vm16 = (_Float16*)alloc(12582912ull * 2);
  _Float16* Ks   = (_Float16*)alloc(1572864ull * 2);
  _Float16* Vt   = (_Float16*)alloc(1572864ull * 2);
  _Float16* outp = (_Float16*)alloc(12582912ull * 2);

  k_cast16<<<dim3(12288), dim3(256), 0, stream>>>(x, x16, 3145728);
  k_cast16<<<dim3(1728), dim3(256), 0, stream>>>(Wqkv, wq16, 442368);
  k_cast16<<<dim3(256), dim3(256), 0, stream>>>(Wv, wv16, 65536);
  k_cast16<<<dim3(576), dim3(256), 0, stream>>>(Wproj, wp16, 147456);
  k_gemm_qkv<<<dim3(18, 128), dim3(256), 0, stream>>>(x16, wq16, q16, k16, v016);
  k_veins<<<dim3(768), dim3(256), 0, stream>>>(k16, v016, wv16, bv, vm16);
  k_segments<<<dim3(96), dim3(256), 0, stream>>>(k16, vm16, Ks, Vt);
  k_attn2<<<dim3(32, 96), dim3(256), 0, stream>>>(q16, k16, vm16, Ks, Vt, outp);
  k_gemm_proj<<<dim3(6, 128), dim3(256), 0, stream>>>(outp, wp16, out);
}

// Round 8
// 340.379 us; speedup vs baseline: 1.3762x; 1.0465x over previous
//
#include <hip/hip_runtime.h>

// FixSetLinearAttention: B=8 T=2048 C=768 NH=12 hs=64 Lmin=16, 255 segments + tail.
// R8: attn2 LDS 56.3->53KB (3 blocks/CU; P stride 280, 16-col tail block with
// P-side clamp), exp2-domain softmax, setprio around MFMA clusters. qkv/proj get
// 1D grid + bijective XCD-chunk swizzle (A-panel stays in one XCD's L2).

typedef float  f32x4  __attribute__((ext_vector_type(4)));
typedef _Float16 half8 __attribute__((ext_vector_type(8)));
typedef _Float16 half4 __attribute__((ext_vector_type(4)));

#define DEV __device__ __forceinline__
#define MFMA16(a, b, c) __builtin_amdgcn_mfma_f32_16x16x32_f16((a), (b), (c), 0, 0, 0)
#define GLOAD16(gp, lp)                                                  \
  __builtin_amdgcn_global_load_lds(                                      \
      (const __attribute__((address_space(1))) unsigned int*)(gp),       \
      (__attribute__((address_space(3))) unsigned int*)(lp), 16, 0, 0)

// ---------------- prep: f32 -> fp16 ----------------
__global__ __launch_bounds__(256) void k_cast16(const float* __restrict__ in,
                                                _Float16* __restrict__ outh, int n4) {
  int i = blockIdx.x * 256 + threadIdx.x;
  if (i >= n4) return;
  f32x4 v = ((const f32x4*)in)[i];
  half4 o;
#pragma unroll
  for (int c = 0; c < 4; ++c) o[c] = (_Float16)v[c];
  ((half4*)outh)[i] = o;
}

// ---------------- qkv GEMM: C = A @ B^T, fp16, XCD-chunked 1D grid ----------------
__global__ __launch_bounds__(256, 3) void k_gemm_qkv(
    const _Float16* __restrict__ A16, const _Float16* __restrict__ B16,
    _Float16* __restrict__ qo, _Float16* __restrict__ ko, _Float16* __restrict__ v0o) {
  __shared__ _Float16 sA[128][64], sB[128][64];
  const int K = 768;
  int tid = threadIdx.x, lane = tid & 63, wave = tid >> 6;
  int l15 = lane & 15, g = lane >> 4;
  int wr = wave >> 1, wc = wave & 1;
  // 2304 blocks = 8 XCDs x 288; each XCD owns a contiguous m-range (A-panel L2-resident)
  int wg = (blockIdx.x & 7) * 288 + (blockIdx.x >> 3);
  int n0 = (wg % 18) * 128, m0 = (wg / 18) * 128;
  f32x4 acc[4][4];
#pragma unroll
  for (int a = 0; a < 4; ++a)
#pragma unroll
    for (int b = 0; b < 4; ++b) acc[a][b] = f32x4{0.f, 0.f, 0.f, 0.f};
  int rsel = lane >> 3;            // row within 8-row group; row&7 == rsel
  int csel = (lane & 7) ^ rsel;    // pre-swizzled source chunk
  for (int k0 = 0; k0 < K; k0 += 64) {
#pragma unroll
    for (int r = 0; r < 4; ++r) {
      int row = wave * 32 + r * 8 + rsel;
      GLOAD16(&A16[(size_t)(m0 + row) * K + k0 + csel * 8], &sA[wave * 32 + r * 8][0]);
      GLOAD16(&B16[(size_t)(n0 + row) * K + k0 + csel * 8], &sB[wave * 32 + r * 8][0]);
    }
    __syncthreads();
#pragma unroll
    for (int kk = 0; kk < 2; ++kk) {
      int kc = kk * 4 + g;
      int cc = ((kc ^ (l15 & 7)) << 3);
      half8 af[4], bf[4];
#pragma unroll
      for (int mf = 0; mf < 4; ++mf) af[mf] = *(const half8*)&sA[wr * 64 + mf * 16 + l15][cc];
#pragma unroll
      for (int nf = 0; nf < 4; ++nf) bf[nf] = *(const half8*)&sB[wc * 64 + nf * 16 + l15][cc];
#pragma unroll
      for (int mf = 0; mf < 4; ++mf)
#pragma unroll
        for (int nf = 0; nf < 4; ++nf)
          acc[mf][nf] = MFMA16(af[mf], bf[nf], acc[mf][nf]);
    }
    __syncthreads();
  }
  int sec = n0 / 768;
  int nb = n0 - sec * 768;
#pragma unroll
  for (int mf = 0; mf < 4; ++mf)
#pragma unroll
    for (int nf = 0; nf < 4; ++nf)
#pragma unroll
      for (int r = 0; r < 4; ++r) {
        int m = m0 + wr * 64 + mf * 16 + (g << 2) + r;
        int n = nb + wc * 64 + nf * 16 + l15;
        int b = m >> 11, t = m & 2047;
        int h = n >> 6, d = n & 63;
        size_t idx = (((size_t)b * 12 + h) * 2048 + t) * 64 + d;
        _Float16 val = (_Float16)acc[mf][nf][r];
        if (sec == 0) qo[idx] = val;
        else if (sec == 1) ko[idx] = val;
        else v0o[idx] = val;
      }
}

// ---------------- v = (k (x) v0) @ Wv^T + bv  (fp16, LDS-shared B tiles) ----------------
__global__ __launch_bounds__(256, 3) void k_veins(
    const _Float16* __restrict__ kh, const _Float16* __restrict__ v0g,
    const _Float16* __restrict__ Wvh, const float* __restrict__ bv,
    _Float16* __restrict__ vout) {
  __shared__ _Float16 ks[256][72];     // 36 KB
  __shared__ _Float16 sB[2][64][64];   // 16 KB, XOR-chunk swizzled
  int tid = threadIdx.x, lane = tid & 63, wave = tid >> 6;
  int l15 = lane & 15, g = lane >> 4, g8 = g << 3;
  size_t row0 = (size_t)blockIdx.x * 256;

  int srow_lo = wave * 8 + (lane >> 3);
  int scsrc = (lane & 7) ^ (lane >> 3);
  auto STAGE = [&](int b, int i) {
#pragma unroll
    for (int h = 0; h < 2; ++h) {
      GLOAD16(&Wvh[(size_t)(h * 32 + srow_lo) * 4096 + i * 64 + (scsrc << 3)],
              ((_Float16*)sB) + (size_t)b * 4096 + (h * 256 + wave * 64) * 8);
    }
  };

#pragma unroll
  for (int r = 0; r < 8; ++r) {
    int row = (tid >> 3) + r * 32;
    int c8 = (tid & 7) << 3;
    *(half8*)&ks[row][c8] = *(const half8*)&kh[(row0 + row) * 64 + c8];
  }
  half8 v0r[4][2];
#pragma unroll
  for (int mf = 0; mf < 4; ++mf) {
    size_t rb = (row0 + wave * 64 + mf * 16 + l15) * 64;
#pragma unroll
    for (int kk = 0; kk < 2; ++kk)
      v0r[mf][kk] = *(const half8*)&v0g[rb + kk * 32 + g8];
  }
  f32x4 acc[4][4];
#pragma unroll
  for (int a = 0; a < 4; ++a)
#pragma unroll
    for (int b = 0; b < 4; ++b) acc[a][b] = f32x4{0.f, 0.f, 0.f, 0.f};

  STAGE(0, 0);
  __syncthreads();
  int r0 = wave * 64 + l15;
  for (int i8 = 0; i8 < 8; ++i8) {
    half8 kr0 = *(const half8*)&ks[r0][i8 * 8];
    half8 kr1 = *(const half8*)&ks[r0 + 16][i8 * 8];
    half8 kr2 = *(const half8*)&ks[r0 + 32][i8 * 8];
    half8 kr3 = *(const half8*)&ks[r0 + 48][i8 * 8];
#pragma unroll
    for (int ii = 0; ii < 8; ++ii) {
      int i = i8 * 8 + ii;
      int cur = i & 1;
      if (i < 63) STAGE(cur ^ 1, i + 1);
      half8 b0[4], b1[4];
#pragma unroll
      for (int nf = 0; nf < 4; ++nf) {
        b0[nf] = *(const half8*)&sB[cur][nf * 16 + l15][((g ^ (l15 & 7)) << 3)];
        b1[nf] = *(const half8*)&sB[cur][nf * 16 + l15][(((4 + g) ^ (l15 & 7)) << 3)];
      }
      _Float16 kv0 = kr0[ii], kv1 = kr1[ii], kv2 = kr2[ii], kv3 = kr3[ii];
      {
        half8 a0 = v0r[0][0] * kv0, a1 = v0r[1][0] * kv1;
        half8 a2 = v0r[2][0] * kv2, a3 = v0r[3][0] * kv3;
#pragma unroll
        for (int nf = 0; nf < 4; ++nf) {
          acc[0][nf] = MFMA16(a0, b0[nf], acc[0][nf]);
          acc[1][nf] = MFMA16(a1, b0[nf], acc[1][nf]);
          acc[2][nf] = MFMA16(a2, b0[nf], acc[2][nf]);
          acc[3][nf] = MFMA16(a3, b0[nf], acc[3][nf]);
        }
      }
      {
        half8 a0 = v0r[0][1] * kv0, a1 = v0r[1][1] * kv1;
        half8 a2 = v0r[2][1] * kv2, a3 = v0r[3][1] * kv3;
#pragma unroll
        for (int nf = 0; nf < 4; ++nf) {
          acc[0][nf] = MFMA16(a0, b1[nf], acc[0][nf]);
          acc[1][nf] = MFMA16(a1, b1[nf], acc[1][nf]);
          acc[2][nf] = MFMA16(a2, b1[nf], acc[2][nf]);
          acc[3][nf] = MFMA16(a3, b1[nf], acc[3][nf]);
        }
      }
      __syncthreads();
    }
  }
#pragma unroll
  for (int mf = 0; mf < 4; ++mf)
#pragma unroll
    for (int nf = 0; nf < 4; ++nf) {
      int e = (nf << 4) + l15;
      float bve = bv[e];
#pragma unroll
      for (int r = 0; r < 4; ++r) {
        int row = wave * 64 + mf * 16 + (g << 2) + r;
        vout[(row0 + row) * 64 + e] = (_Float16)(acc[mf][nf][r] + bve);
      }
    }
}

// ---------------- segment sums -> Ks fp16 [bh][256][64], Vt fp16 [bh][64][256] ----------------
__global__ __launch_bounds__(256) void k_segments(
    const _Float16* __restrict__ kmat, const _Float16* __restrict__ vmat,
    _Float16* __restrict__ Ks, _Float16* __restrict__ Vt) {
  __shared__ float Ls[255][64];
  int bh = blockIdx.x, tid = threadIdx.x;
  size_t bh2048 = (size_t)bh * 2048;
  // ---- K ----
  for (int task = tid; task < 8192; task += 256) {
    int seg = task >> 6, d = task & 63;
    const _Float16* p = kmat + (bh2048 + seg * 16) * 64 + d;
    float s = 0.f;
#pragma unroll
    for (int u = 0; u < 16; ++u) s += (float)p[u * 64];
    Ls[seg][d] = s;
  }
  __syncthreads();
  {
    int bprev = 0, bcur = 128, cnt = 64;
    for (int lev = 1; lev < 8; ++lev) {
      for (int task = tid; task < cnt * 64; task += 256) {
        int i = task >> 6, d = task & 63;
        Ls[bcur + i][d] = Ls[bprev + 2 * i][d] + Ls[bprev + 2 * i + 1][d];
      }
      __syncthreads();
      bprev = bcur; bcur += cnt; cnt >>= 1;
    }
  }
  for (int task = tid; task < 16384; task += 256) {
    int seg = task >> 6;
    float v = (seg < 255) ? Ls[seg][task & 63] : 0.f;
    Ks[(size_t)bh * 16384 + task] = (_Float16)v;
  }
  __syncthreads();
  // ---- V ----
  for (int task = tid; task < 8192; task += 256) {
    int seg = task >> 6, d = task & 63;
    const _Float16* p = vmat + (bh2048 + seg * 16) * 64 + d;
    float s = 0.f;
#pragma unroll
    for (int u = 0; u < 16; ++u) s += (float)p[u * 64];
    Ls[seg][d] = s;
  }
  __syncthreads();
  {
    int bprev = 0, bcur = 128, cnt = 64;
    for (int lev = 1; lev < 8; ++lev) {
      for (int task = tid; task < cnt * 64; task += 256) {
        int i = task >> 6, d = task & 63;
        Ls[bcur + i][d] = Ls[bprev + 2 * i][d] + Ls[bprev + 2 * i + 1][d];
      }
      __syncthreads();
      bprev = bcur; bcur += cnt; cnt >>= 1;
    }
  }
  for (int task = tid; task < 16384; task += 256) {
    int d = task >> 8, seg = task & 255;
    float v = (seg < 255) ? Ls[seg][d] : 0.f;
    Vt[(size_t)bh * 16384 + task] = (_Float16)v;
  }
}

// ---------------- MFMA attention (fp16): block = (bh, 64-tok tile), 4 waves ----------------
// LDS 53KB -> 3 blocks/CU. Softmax in exp2 domain. Tail-P block 16 cols (P-side clamp).
__global__ __launch_bounds__(256) void k_attn2(
    const _Float16* __restrict__ qm, const _Float16* __restrict__ km,
    const _Float16* __restrict__ vm,
    const _Float16* __restrict__ Ks, const _Float16* __restrict__ Vt,
    _Float16* __restrict__ outp) {
  __shared__ __align__(16) _Float16 P[4][16][280];   // 35840 B (stride 140dw: 2-way max)
  __shared__ __align__(16) _Float16 tK[4][16][72];   //  9216 B
  __shared__ __align__(16) _Float16 tV[4][16][72];   //  9216 B  => 54272 total
  int tid = threadIdx.x, lane = tid & 63, wave = tid >> 6;
  int orig = blockIdx.y * 32 + blockIdx.x;
  int wg = (orig & 7) * 384 + (orig >> 3);  // XCD-chunked swizzle (3072 = 8*384)
  int tile = wg & 31, bh = wg >> 5;
  int t0 = tile * 64, tw0 = t0 + wave * 16;
  size_t bh2048 = (size_t)bh * 2048;
  int l15 = lane & 15, g = lane >> 4, g8 = g << 3;

  // per-wave tail prefixes (lane = d)
  {
    const _Float16* kp = km + (bh2048 + tw0) * 64 + lane;
    const _Float16* vp = vm + (bh2048 + tw0) * 64 + lane;
    float ka = 0.f, va = 0.f;
#pragma unroll
    for (int t = 0; t < 16; ++t) {
      ka += (float)kp[t * 64];
      va += (float)vp[t * 64];
      tK[wave][t][lane] = (_Float16)ka;
      tV[wave][t][lane] = (_Float16)va;
    }
  }
  // Q fragments
  half8 qf[2];
  {
    const _Float16* qp = qm + (bh2048 + tw0 + l15) * 64 + g8;
    qf[0] = *(const half8*)qp;
    qf[1] = *(const half8*)(qp + 32);
  }
  // validity masks
  unsigned mA = 0, mE = 0;
#pragma unroll
  for (int nf = 0; nf < 16; ++nf) {
    int seg = nf * 16 + l15;
    if (seg < 255) {
      int m = 256 - seg;
      int cl = 32 - __clz(m - 1);
      int lev = 8 - cl;
      int rdx = (seg - (256 - (256 >> lev)) + 1) * (16 << lev) - 1;
      if (rdx < tw0) mA |= 1u << nf;
      else if (rdx == tw0 + 15) mE |= 1u << nf;
    }
  }
  unsigned mAny = mA | mE;
  unsigned pmask = 0;
#pragma unroll
  for (int ks = 0; ks < 8; ++ks)
    if (__any((int)((mAny >> (2 * ks)) & 3u))) pmask |= 1u << ks;

  // ---- QK^T ----
  f32x4 acc[17];
#pragma unroll
  for (int i = 0; i < 17; ++i) acc[i] = f32x4{0.f, 0.f, 0.f, 0.f};
  const _Float16* KsB = Ks + (size_t)bh * 16384;
  __builtin_amdgcn_s_setprio(1);
#pragma unroll
  for (int ks = 0; ks < 8; ++ks) {
    if ((pmask >> ks) & 1) {
      const _Float16* ph = KsB + (size_t)(ks * 32 + l15) * 64 + g8;
      half8 h00 = *(const half8*)ph;
      half8 h01 = *(const half8*)(ph + 32);
      half8 h10 = *(const half8*)(ph + 1024);
      half8 h11 = *(const half8*)(ph + 1056);
      acc[2 * ks] = MFMA16(qf[0], h00, acc[2 * ks]);
      acc[2 * ks] = MFMA16(qf[1], h01, acc[2 * ks]);
      acc[2 * ks + 1] = MFMA16(qf[0], h10, acc[2 * ks + 1]);
      acc[2 * ks + 1] = MFMA16(qf[1], h11, acc[2 * ks + 1]);
    }
  }
  {  // tail fragment (nf=16)
    const _Float16* tp = &tK[wave][l15][g8];
    half8 t0f = *(const half8*)tp;
    half8 t1f = *(const half8*)(tp + 32);
    acc[16] = MFMA16(qf[0], t0f, acc[16]);
    acc[16] = MFMA16(qf[1], t1f, acc[16]);
  }
  __builtin_amdgcn_s_setprio(0);

  // ---- softmax (f32, exp2 domain: c = scale*log2e) ----
  const float c = 0.125f * 1.44269504f;
  float mx[4], sm[4], et[4];
#pragma unroll
  for (int r = 0; r < 4; ++r) {
    int tr = g * 4 + r;
    mx[r] = (l15 == tr) ? acc[16][r] * c : -3.0e38f;
  }
#pragma unroll
  for (int nf = 0; nf < 16; ++nf) {
    bool bA = (mA >> nf) & 1, bE = (mE >> nf) & 1;
#pragma unroll
    for (int r = 0; r < 4; ++r) {
      bool u = bA || (bE && g == 3 && r == 3);
      if (u) mx[r] = fmaxf(mx[r], acc[nf][r] * c);
    }
  }
#pragma unroll
  for (int off = 1; off < 16; off <<= 1)
#pragma unroll
    for (int r = 0; r < 4; ++r) mx[r] = fmaxf(mx[r], __shfl_xor(mx[r], off));
#pragma unroll
  for (int r = 0; r < 4; ++r) {
    int tr = g * 4 + r;
    et[r] = (l15 == tr) ? exp2f(acc[16][r] * c - mx[r]) : 0.f;
    sm[r] = et[r];
  }
#pragma unroll
  for (int ks = 0; ks < 8; ++ks) {
    if ((pmask >> ks) & 1) {
#pragma unroll
      for (int f = 0; f < 2; ++f) {
        int nf = 2 * ks + f;
        bool bA = (mA >> nf) & 1, bE = (mE >> nf) & 1;
#pragma unroll
        for (int r = 0; r < 4; ++r) {
          bool u = bA || (bE && g == 3 && r == 3);
          float e = u ? exp2f(acc[nf][r] * c - mx[r]) : 0.f;
          acc[nf][r] = e;
          sm[r] += e;
        }
      }
    }
  }
#pragma unroll
  for (int off = 1; off < 16; off <<= 1)
#pragma unroll
    for (int r = 0; r < 4; ++r) sm[r] += __shfl_xor(sm[r], off);
  float inv[4];
#pragma unroll
  for (int r = 0; r < 4; ++r) inv[r] = 1.f / sm[r];

  // ---- P writes (per-wave LDS) ----
  {  // zero 16-col tail block: 64 lanes x half4 = 16 rows x 16 cols
    half4 z4 = {};
    *(half4*)&P[wave][lane >> 2][256 + (lane & 3) * 4] = z4;
  }
#pragma unroll
  for (int nf = 0; nf < 16; ++nf)
#pragma unroll
    for (int r = 0; r < 4; ++r)
      P[wave][g * 4 + r][nf * 16 + l15] = (_Float16)(acc[nf][r] * inv[r]);
#pragma unroll
  for (int r = 0; r < 4; ++r)
    if (l15 == g * 4 + r) P[wave][l15][256 + l15] = (_Float16)(et[r] * inv[r]);

  // ---- PV ----
  f32x4 oa[4];
#pragma unroll
  for (int i = 0; i < 4; ++i) oa[i] = f32x4{0.f, 0.f, 0.f, 0.f};
  const _Float16* VB = Vt + (size_t)bh * 16384;
  __builtin_amdgcn_s_setprio(1);
#pragma unroll
  for (int ks = 0; ks < 8; ++ks) {
    if ((pmask >> ks) & 1) {
      half8 pa = *(const half8*)&P[wave][l15][ks * 32 + g8];
#pragma unroll
      for (int n2 = 0; n2 < 4; ++n2) {
        half8 vb = *(const half8*)(VB + (size_t)(n2 * 16 + l15) * 256 + ks * 32 + g8);
        oa[n2] = MFMA16(pa, vb, oa[n2]);
      }
    }
  }
  {  // tail k-step: pa clamped to 16 cols (g>=2 re-reads, masked by vt=0 there)
    half8 pa = *(const half8*)&P[wave][l15][256 + (g & 1) * 8];
#pragma unroll
    for (int n2 = 0; n2 < 4; ++n2) {
      half8 vt = {};
      if (g < 2) {
#pragma unroll
        for (int jj = 0; jj < 8; ++jj) vt[jj] = tV[wave][g8 + jj][n2 * 16 + l15];
      }
      oa[n2] = MFMA16(pa, vt, oa[n2]);
    }
  }
  __builtin_amdgcn_s_setprio(0);
  // ---- output ----
  int b = bh / 12, h = bh - b * 12;
  size_t obase = ((size_t)b * 2048 + tw0) * 768 + h * 64;
#pragma unroll
  for (int n2 = 0; n2 < 4; ++n2)
#pragma unroll
    for (int r = 0; r < 4; ++r)
      outp[obase + (size_t)(g * 4 + r) * 768 + n2 * 16 + l15] = (_Float16)oa[n2][r];
}

// ---------------- proj GEMM: d_out = out_pre @ Wproj^T (fp16, XCD-chunked) ----------------
__global__ __launch_bounds__(256, 3) void k_gemm_proj(
    const _Float16* __restrict__ A16, const _Float16* __restrict__ B16,
    float* __restrict__ C) {
  __shared__ _Float16 sA[128][64], sB[128][64];
  const int K = 768;
  int tid = threadIdx.x, lane = tid & 63, wave = tid >> 6;
  int l15 = lane & 15, g = lane >> 4;
  int wr = wave >> 1, wc = wave & 1;
  // 768 blocks = 8 XCDs x 96; contiguous m-range per XCD
  int wg = (blockIdx.x & 7) * 96 + (blockIdx.x >> 3);
  int n0 = (wg % 6) * 128, m0 = (wg / 6) * 128;
  f32x4 acc[4][4];
#pragma unroll
  for (int a = 0; a < 4; ++a)
#pragma unroll
    for (int b = 0; b < 4; ++b) acc[a][b] = f32x4{0.f, 0.f, 0.f, 0.f};
  int rsel = lane >> 3;
  int csel = (lane & 7) ^ rsel;
  for (int k0 = 0; k0 < K; k0 += 64) {
#pragma unroll
    for (int r = 0; r < 4; ++r) {
      int row = wave * 32 + r * 8 + rsel;
      GLOAD16(&A16[(size_t)(m0 + row) * K + k0 + csel * 8], &sA[wave * 32 + r * 8][0]);
      GLOAD16(&B16[(size_t)(n0 + row) * K + k0 + csel * 8], &sB[wave * 32 + r * 8][0]);
    }
    __syncthreads();
#pragma unroll
    for (int kk = 0; kk < 2; ++kk) {
      int kc = kk * 4 + g;
      int cc = ((kc ^ (l15 & 7)) << 3);
      half8 af[4], bf[4];
#pragma unroll
      for (int mf = 0; mf < 4; ++mf) af[mf] = *(const half8*)&sA[wr * 64 + mf * 16 + l15][cc];
#pragma unroll
      for (int nf = 0; nf < 4; ++nf) bf[nf] = *(const half8*)&sB[wc * 64 + nf * 16 + l15][cc];
#pragma unroll
      for (int mf = 0; mf < 4; ++mf)
#pragma unroll
        for (int nf = 0; nf < 4; ++nf)
          acc[mf][nf] = MFMA16(af[mf], bf[nf], acc[mf][nf]);
    }
    __syncthreads();
  }
#pragma unroll
  for (int mf = 0; mf < 4; ++mf)
#pragma unroll
    for (int nf = 0; nf < 4; ++nf)
#pragma unroll
      for (int r = 0; r < 4; ++r) {
        int m = m0 + wr * 64 + mf * 16 + (g << 2) + r;
        int n = n0 + wc * 64 + nf * 16 + l15;
        C[(size_t)m * 768 + n] = acc[mf][nf][r];
      }
}

// ---------------- host launch ----------------
extern "C" void kernel_launch(void* const* d_in, const int* in_sizes, int n_in,
                              void* d_out, int out_size, void* d_ws, size_t ws_size,
                              hipStream_t stream) {
  const float* x = (const float*)d_in[0];
  const float* Wqkv = (const float*)d_in[1];
  const float* Wproj = (const float*)d_in[2];
  const float* Wv = (const float*)d_in[3];
  const float* bv = (const float*)d_in[4];
  float* out = (float*)d_out;
  char* ws = (char*)d_ws;
  size_t off = 0;
  auto alloc = [&](size_t bytes) -> void* {
    void* p = (void*)(ws + off);
    off += (bytes + 255) & ~(size_t)255;
    return p;
  };
  _Float16* x16  = (_Float16*)alloc(12582912ull * 2);
  _Float16* wq16 = (_Float16*)alloc(1769472ull * 2);
  _Float16* wv16 = (_Float16*)alloc(262144ull * 2 + 8192);
  _Float16* wp16 = (_Float16*)alloc(589824ull * 2);
  _Float16* q16  = (_Float16*)alloc(12582912ull * 2);
  _Float16* k16  = (_Float16*)alloc(12582912ull * 2);
  _Float16* v016 = (_Float16*)alloc(12582912ull * 2);
  _Float16* vm16 = (_Float16*)alloc(12582912ull * 2);
  _Float16* Ks   = (_Float16*)alloc(1572864ull * 2);
  _Float16* Vt   = (_Float16*)alloc(1572864ull * 2);
  _Float16* outp = (_Float16*)alloc(12582912ull * 2);

  k_cast16<<<dim3(12288), dim3(256), 0, stream>>>(x, x16, 3145728);
  k_cast16<<<dim3(1728), dim3(256), 0, stream>>>(Wqkv, wq16, 442368);
  k_cast16<<<dim3(256), dim3(256), 0, stream>>>(Wv, wv16, 65536);
  k_cast16<<<dim3(576), dim3(256), 0, stream>>>(Wproj, wp16, 147456);
  k_gemm_qkv<<<dim3(2304), dim3(256), 0, stream>>>(x16, wq16, q16, k16, v016);
  k_veins<<<dim3(768), dim3(256), 0, stream>>>(k16, v016, wv16, bv, vm16);
  k_segments<<<dim3(96), dim3(256), 0, stream>>>(k16, vm16, Ks, Vt);
  k_attn2<<<dim3(32, 96), dim3(256), 0, stream>>>(q16, k16, vm16, Ks, Vt, outp);
  k_gemm_proj<<<dim3(768), dim3(256), 0, stream>>>(outp, wp16, out);
}